// Round 6
// baseline (353.169 us; speedup 1.0000x reference)
//
#include <hip/hip_runtime.h>
#include <cmath>

#define SEQ 2048
#define BATCH 2
#define HID 1024
#define NH 16
#define NKV 4
#define DH 64
#define KVDIM 256
#define K32C 32          // K=1024 -> 32 chunks of 32

typedef __attribute__((ext_vector_type(8))) short bf16x8;
typedef __attribute__((ext_vector_type(4))) float f32x4;

static __device__ __forceinline__ unsigned short f2bf(float x) {
  union { float f; unsigned u; } v; v.f = x;
  unsigned r = v.u + 0x7fffu + ((v.u >> 16) & 1u);  // RNE
  return (unsigned short)(r >> 16);
}
static __device__ __forceinline__ float bf2f(unsigned short h) {
  union { unsigned u; float f; } v; v.u = ((unsigned)h) << 16;
  return v.f;
}
static __device__ __forceinline__ void gl_lds16(const unsigned short* g, unsigned short* l) {
  __builtin_amdgcn_global_load_lds(
      (const __attribute__((address_space(1))) unsigned int*)g,
      (__attribute__((address_space(3))) unsigned int*)l, 16, 0, 0);
}

// ---- pack A (fp32 [M][K=1024] row-major -> MFMA-A-frag-major bf16 hi[,lo]) ----
template<bool HILO>
__global__ __launch_bounds__(256) void pack_a_kernel(
    const float* __restrict__ A, unsigned short* __restrict__ hi,
    unsigned short* __restrict__ lo) {
  int gid = blockIdx.x * 256 + threadIdx.x;
  int lane = gid & 63;
  int k32 = (gid >> 6) & 31;
  int m16 = gid >> 11;
  int quad = lane >> 4, l16 = lane & 15;
  const float* src = A + (size_t)(m16 * 16 + l16) * 1024 + k32 * 32 + quad * 8;
  float4 a0 = *(const float4*)src;
  float4 a1 = *(const float4*)(src + 4);
  float v[8] = {a0.x, a0.y, a0.z, a0.w, a1.x, a1.y, a1.z, a1.w};
  unsigned short h[8], l[8];
#pragma unroll
  for (int j = 0; j < 8; ++j) {
    h[j] = f2bf(v[j]);
    if (HILO) l[j] = f2bf(v[j] - bf2f(h[j]));
  }
  *(bf16x8*)(hi + (size_t)gid * 8) = *(bf16x8*)h;
  if (HILO) *(bf16x8*)(lo + (size_t)gid * 8) = *(bf16x8*)l;
}

// ---- pack A from TRANSPOSED attention partials [b][h][d][q], normalize by l ----
__global__ __launch_bounds__(256) void pack_a_norm_kernel(
    const float* __restrict__ At, const float* __restrict__ lpart,
    unsigned short* __restrict__ hi, unsigned short* __restrict__ lo) {
  int gid = blockIdx.x * 256 + threadIdx.x;
  int lane = gid & 63;
  int k32 = (gid >> 6) & 31;
  int m16 = gid >> 11;
  int quad = lane >> 4, l16 = lane & 15;
  int m = m16 * 16 + l16;
  int b = m >> 11, s = m & 2047;
  int k0 = k32 * 32 + quad * 8;
  int h = k0 >> 6, d0 = k0 & 63;
  float inv = 1.0f / lpart[(size_t)(b * NH + h) * SEQ + s];
  const float* src = At + ((size_t)(b * NH + h) * DH + d0) * SEQ + s;
  unsigned short hh[8], ll[8];
#pragma unroll
  for (int j = 0; j < 8; ++j) {
    float x = src[(size_t)j * SEQ] * inv;
    hh[j] = f2bf(x);
    ll[j] = f2bf(x - bf2f(hh[j]));
  }
  *(bf16x8*)(hi + (size_t)gid * 8) = *(bf16x8*)hh;
  *(bf16x8*)(lo + (size_t)gid * 8) = *(bf16x8*)ll;
}

// ---- pack B (fp32 W [K=1024][Nsrc] -> MFMA-B-frag-major bf16 hi[,lo]) ----
template<bool HILO>
__global__ __launch_bounds__(256) void pack_b_kernel(
    const float* __restrict__ W, unsigned short* __restrict__ hi,
    unsigned short* __restrict__ lo, int Nsrc) {
  int gid = blockIdx.x * 256 + threadIdx.x;
  int lane = gid & 63;
  int k32 = (gid >> 6) & 31;
  int n16 = gid >> 11;
  int quad = lane >> 4, l16 = lane & 15;
  int n = n16 * 16 + l16, k = k32 * 32 + quad * 8;
  unsigned short h[8], l[8];
#pragma unroll
  for (int j = 0; j < 8; ++j) {
    float v = W[(size_t)(k + j) * Nsrc + n];
    h[j] = f2bf(v);
    if (HILO) l[j] = f2bf(v - bf2f(h[j]));
  }
  *(bf16x8*)(hi + (size_t)gid * 8) = *(bf16x8*)h;
  if (HILO) *(bf16x8*)(lo + (size_t)gid * 8) = *(bf16x8*)l;
}

__global__ __launch_bounds__(256) void bias_cat_kernel(
    const float* __restrict__ bq, const float* __restrict__ bk,
    const float* __restrict__ bv, float* __restrict__ dst) {
  int n = blockIdx.x * 256 + threadIdx.x;
  if (n < 1536)
    dst[n] = (n < 1024) ? bq[n] : (n < 1280 ? bk[n - 1024] : bv[n - 1280]);
}

// ---- packed-input MFMA GEMM (unchanged) ----
template<int CHAINS, bool OUTBF16>
__global__ __launch_bounds__(256) void gemm_pk_kernel(
    const unsigned short* __restrict__ Ah, const unsigned short* __restrict__ Al,
    const unsigned short* __restrict__ Bh, const unsigned short* __restrict__ Bl,
    const float* __restrict__ bias, void* __restrict__ Cout, int N) {
  constexpr int NCH = (CHAINS == 3) ? 2 : 1;
  __shared__ unsigned short Asm[NCH][4 * 512];
  __shared__ unsigned short Bsm[NCH][8 * 512];
  const int tid = threadIdx.x;
  const int wave = tid >> 6, lane = tid & 63;
  const int wr = wave >> 1, wc = wave & 1;
  const int quad = lane >> 4, l16 = lane & 15;
  const size_t abase = ((size_t)(blockIdx.y * 4 + wave) * K32C) * 64 + lane;
  const size_t bbase0 = ((size_t)(blockIdx.x * 8 + wave) * K32C) * 64 + lane;
  const size_t bbase1 = ((size_t)(blockIdx.x * 8 + wave + 4) * K32C) * 64 + lane;
  f32x4 acc[2][4] = {};
  for (int k32 = 0; k32 < K32C; ++k32) {
    __syncthreads();
    gl_lds16(Ah + (abase + (size_t)k32 * 64) * 8, &Asm[0][wave * 512]);
    gl_lds16(Bh + (bbase0 + (size_t)k32 * 64) * 8, &Bsm[0][wave * 512]);
    gl_lds16(Bh + (bbase1 + (size_t)k32 * 64) * 8, &Bsm[0][(wave + 4) * 512]);
    if (CHAINS == 3) {
      gl_lds16(Al + (abase + (size_t)k32 * 64) * 8, &Asm[1][wave * 512]);
      gl_lds16(Bl + (bbase0 + (size_t)k32 * 64) * 8, &Bsm[1][wave * 512]);
      gl_lds16(Bl + (bbase1 + (size_t)k32 * 64) * 8, &Bsm[1][(wave + 4) * 512]);
    }
    __syncthreads();
    bf16x8 af[2][NCH], bfr[4][NCH];
#pragma unroll
    for (int mt = 0; mt < 2; ++mt)
#pragma unroll
      for (int ch = 0; ch < NCH; ++ch)
        af[mt][ch] = *(const bf16x8*)&Asm[ch][((wr * 2 + mt) * 64 + lane) * 8];
#pragma unroll
    for (int nt = 0; nt < 4; ++nt)
#pragma unroll
      for (int ch = 0; ch < NCH; ++ch)
        bfr[nt][ch] = *(const bf16x8*)&Bsm[ch][((wc * 4 + nt) * 64 + lane) * 8];
#pragma unroll
    for (int mt = 0; mt < 2; ++mt)
#pragma unroll
      for (int nt = 0; nt < 4; ++nt) {
        acc[mt][nt] = __builtin_amdgcn_mfma_f32_16x16x32_bf16(af[mt][0], bfr[nt][0], acc[mt][nt], 0, 0, 0);
        if (CHAINS == 3) {
          acc[mt][nt] = __builtin_amdgcn_mfma_f32_16x16x32_bf16(af[mt][1], bfr[nt][0], acc[mt][nt], 0, 0, 0);
          acc[mt][nt] = __builtin_amdgcn_mfma_f32_16x16x32_bf16(af[mt][0], bfr[nt][1], acc[mt][nt], 0, 0, 0);
        }
      }
  }
  const int n0 = blockIdx.x * 128 + wc * 64;
  const int m0 = blockIdx.y * 64 + wr * 32;
#pragma unroll
  for (int mt = 0; mt < 2; ++mt)
#pragma unroll
    for (int nt = 0; nt < 4; ++nt)
#pragma unroll
      for (int r = 0; r < 4; ++r) {
        int gm = m0 + mt * 16 + quad * 4 + r;
        int n = n0 + nt * 16 + l16;
        float v = acc[mt][nt][r] + bias[n];
        if (OUTBF16)
          ((unsigned short*)Cout)[(size_t)gm * N + n] = f2bf(v);
        else
          ((float*)Cout)[(size_t)gm * N + n] = v;
      }
}

// ---- RoPE(half=512) + rmsnorm, Q -> A-frag-major packed bf16 hi/lo ---------
__global__ __launch_bounds__(1024) void rope_norm_q_kernel(
    const unsigned short* __restrict__ qkv, unsigned short* __restrict__ Qh,
    unsigned short* __restrict__ Ql) {
  const int s = blockIdx.x, b = blockIdx.y;
  const int t = threadIdx.x;
  const unsigned short* row = qkv + ((size_t)b * SEQ + s) * 1536;
  const int j = t & 511;
  float invf = exp2f((float)j * (-13.287712379549449f / 512.0f));
  float ang = (float)s * invf;
  float c = cosf(ang), sn = sinf(ang);
  float x1 = bf2f(row[j]), x2 = bf2f(row[j + 512]);
  float val = (t < 512) ? (x1 * c - x2 * sn) : (x2 * c + x1 * sn);
  float ss = val * val;
#pragma unroll
  for (int off = 1; off < 64; off <<= 1) ss += __shfl_xor(ss, off);
  float rn = rsqrtf(ss * (1.0f / 64.0f) + 1.1920929e-07f);
  float v = val * rn;
  unsigned short hi = f2bf(v);
  unsigned short lo = f2bf(v - bf2f(hi));
  int h = t >> 6, d = t & 63;
  size_t o = (size_t)(b * NH + h) * 131072 +
             ((((size_t)(s >> 4) * 2 + (d >> 5)) * 64) + ((d >> 3) & 3) * 16 + (s & 15)) * 8 + (d & 7);
  Qh[o] = hi;
  Ql[o] = lo;
}

// ---- RoPE(half=128)+rmsnorm K -> B-frag-major hi; V -> B-frag-major --------
__global__ __launch_bounds__(256) void rope_norm_kv_kernel(
    const unsigned short* __restrict__ qkv, unsigned short* __restrict__ Kpk,
    unsigned short* __restrict__ Vpk) {
  const int s = blockIdx.x, b = blockIdx.y;
  const int t = threadIdx.x;
  const unsigned short* row = qkv + ((size_t)b * SEQ + s) * 1536;
  const int j = t & 127;
  float invf = exp2f((float)j * (-13.287712379549449f / 128.0f));
  float ang = (float)s * invf;
  float c = cosf(ang), sn = sinf(ang);
  float x1 = bf2f(row[1024 + j]), x2 = bf2f(row[1024 + 128 + j]);
  float val = (t < 128) ? (x1 * c - x2 * sn) : (x2 * c + x1 * sn);
  float ss = val * val;
#pragma unroll
  for (int off = 1; off < 64; off <<= 1) ss += __shfl_xor(ss, off);
  float rn = rsqrtf(ss * (1.0f / 64.0f) + 1.1920929e-07f);
  float kv = val * rn;
  int h = t >> 6, d = t & 63;
  size_t ko = (size_t)(b * NKV + h) * 131072 +
              ((((size_t)(s >> 4) * 2 + (d >> 5)) * 64) + ((d >> 3) & 3) * 16 + (s & 15)) * 8 + (d & 7);
  Kpk[ko] = f2bf(kv);
  size_t vo = (size_t)(b * NKV + h) * 131072 +
              ((((size_t)(d >> 4) * 64 + (s >> 5)) * 64) + ((s >> 3) & 3) * 16 + (d & 15)) * 8 + (s & 7);
  Vpk[vo] = row[1280 + t];
}

// ------------- MFMA attention v4: transposed scores, LDS-free ---------------
// C' = K·Q^T  (A=K-frag, B=Q-frag: our packed layouts serve both roles
// byte-identically). C'-layout: row=j_local=4*quad+r, col=q_local=l16.
//  -> mask loads become coalesced float4 (4 consecutive j at fixed q).
//  -> P^T B-frag for O^T = V^T·P^T built from lanes' own p's via 16 shfl
//     + 8 selects (no LDS round-trip). l = per-lane adds + 2 shfl_xor.
// O^T accumulated to transposed buffer [b][h][d][q] so atomics stay
// lane-coalesced. No LDS, no barriers. Fixed softmax max=8 (rmsnorm bound).
__global__ __launch_bounds__(256, 3) void attn_mfma4_kernel(
    const unsigned short* __restrict__ Qh, const unsigned short* __restrict__ Ql,
    const unsigned short* __restrict__ Kpk, const unsigned short* __restrict__ Vpk,
    const float* __restrict__ mask, float* __restrict__ attn_pot,
    float* __restrict__ l_part) {
  const int b = blockIdx.z;
  const int kvh = blockIdx.y >> 1, jh = blockIdx.y & 1;
  const int q0 = blockIdx.x * 32;
  const int tid = threadIdx.x, wave = tid >> 6, lane = tid & 63;
  const int quad = lane >> 4, l16 = lane & 15;
  const int h = kvh * 4 + wave;

  // Q B-frags (loop-invariant): [qt][kf][hi/lo]
  bf16x8 qbf[2][2][2];
  {
    const unsigned short* Qb_h = Qh + (size_t)(b * NH + h) * 131072;
    const unsigned short* Qb_l = Ql + (size_t)(b * NH + h) * 131072;
#pragma unroll
    for (int qt = 0; qt < 2; ++qt)
#pragma unroll
      for (int kf = 0; kf < 2; ++kf) {
        size_t o = ((((size_t)(q0 >> 4) + qt) * 2 + kf) * 64 + lane) * 8;
        qbf[qt][kf][0] = *(const bf16x8*)(Qb_h + o);
        qbf[qt][kf][1] = *(const bf16x8*)(Qb_l + o);
      }
  }

  const unsigned short* Kb = Kpk + (size_t)(b * NKV + kvh) * 131072;
  const unsigned short* Vb = Vpk + (size_t)(b * NKV + kvh) * 131072;
  const float* mrow0 = mask + ((size_t)b * SEQ + q0 + l16) * SEQ;
  const float* mrow1 = mrow0 + (size_t)16 * SEQ;

  f32x4 O[2][4] = {};            // [qt][d16], C-layout row=d_local, col=q_local
  float lAcc[2] = {0.0f, 0.0f};

  const int jbase = jh * (SEQ / 2);
  constexpr float SC = 0.18033688011112042f;   // 0.125 * log2(e)
  constexpr float L2E = 1.4426950408889634f;   // log2(e)
  constexpr float MOFF = -11.541560327111707f; // -8 * log2(e)
  const int idxA = ((quad & 1) << 5) + l16;    // shfl source lanes for P^T frag
  const int idxB = idxA + 16;
  const bool hi2 = quad >= 2;

#pragma unroll 2
  for (int jc = 0; jc < 32; ++jc) {
    const int j0 = jbase + jc * 32;

    // K A-frags [jt][kf], V^T A-frags [d16], mask float4 [jt][qt]
    bf16x8 kfr[2][2], vfr[4];
#pragma unroll
    for (int jt = 0; jt < 2; ++jt)
#pragma unroll
      for (int kf = 0; kf < 2; ++kf)
        kfr[jt][kf] = *(const bf16x8*)(Kb +
            ((((size_t)(j0 >> 4) + jt) * 2 + kf) * 64 + lane) * 8);
#pragma unroll
    for (int d16 = 0; d16 < 4; ++d16)
      vfr[d16] = *(const bf16x8*)(Vb +
          (((size_t)d16 * 64 + (j0 >> 5)) * 64 + lane) * 8);
    float4 mk[2][2];
#pragma unroll
    for (int jt = 0; jt < 2; ++jt) {
      mk[jt][0] = *(const float4*)(mrow0 + j0 + jt * 16 + quad * 4);
      mk[jt][1] = *(const float4*)(mrow1 + j0 + jt * 16 + quad * 4);
    }

    // QK^T transposed + softmax numerator; pack p's (rounded) into dwords
    unsigned pd[2][2][2];  // [jt][qt][dw]
#pragma unroll
    for (int jt = 0; jt < 2; ++jt)
#pragma unroll
      for (int qt = 0; qt < 2; ++qt) {
        f32x4 C = {};
        C = __builtin_amdgcn_mfma_f32_16x16x32_bf16(kfr[jt][0], qbf[qt][0][0], C, 0, 0, 0);
        C = __builtin_amdgcn_mfma_f32_16x16x32_bf16(kfr[jt][1], qbf[qt][1][0], C, 0, 0, 0);
        C = __builtin_amdgcn_mfma_f32_16x16x32_bf16(kfr[jt][0], qbf[qt][0][1], C, 0, 0, 0);
        C = __builtin_amdgcn_mfma_f32_16x16x32_bf16(kfr[jt][1], qbf[qt][1][1], C, 0, 0, 0);
        float4 m = mk[jt][qt];
        float ms[4] = {m.x, m.y, m.z, m.w};
        unsigned short us[4];
#pragma unroll
        for (int r = 0; r < 4; ++r) {
          float p = exp2f(fmaf(C[r], SC, fmaf(ms[r], L2E, MOFF)));
          us[r] = f2bf(p);
          lAcc[qt] += bf2f(us[r]);   // l consistent with rounded P
        }
        pd[jt][qt][0] = (unsigned)us[0] | ((unsigned)us[1] << 16);
        pd[jt][qt][1] = (unsigned)us[2] | ((unsigned)us[3] << 16);
      }

    // Build P^T B-frags (k=32) from lane-local p's via shfl, then PV
#pragma unroll
    for (int qt = 0; qt < 2; ++qt) {
      unsigned a0 = (unsigned)__shfl((int)pd[0][qt][0], idxA);
      unsigned b0 = (unsigned)__shfl((int)pd[1][qt][0], idxA);
      unsigned a1 = (unsigned)__shfl((int)pd[0][qt][1], idxA);
      unsigned b1 = (unsigned)__shfl((int)pd[1][qt][1], idxA);
      unsigned a2 = (unsigned)__shfl((int)pd[0][qt][0], idxB);
      unsigned b2 = (unsigned)__shfl((int)pd[1][qt][0], idxB);
      unsigned a3 = (unsigned)__shfl((int)pd[0][qt][1], idxB);
      unsigned b3 = (unsigned)__shfl((int)pd[1][qt][1], idxB);
      union { unsigned u[4]; bf16x8 v; } pf;
      pf.u[0] = hi2 ? b0 : a0;
      pf.u[1] = hi2 ? b1 : a1;
      pf.u[2] = hi2 ? b2 : a2;
      pf.u[3] = hi2 ? b3 : a3;
#pragma unroll
      for (int d16 = 0; d16 < 4; ++d16)
        O[qt][d16] = __builtin_amdgcn_mfma_f32_16x16x32_bf16(vfr[d16], pf.v, O[qt][d16], 0, 0, 0);
    }
  }

  // l: reduce partial j-sums across quads (lanes differ in bits 4,5)
#pragma unroll
  for (int qt = 0; qt < 2; ++qt) {
    lAcc[qt] += __shfl_xor(lAcc[qt], 16);
    lAcc[qt] += __shfl_xor(lAcc[qt], 32);
  }
  if (quad == 0) {
#pragma unroll
    for (int qt = 0; qt < 2; ++qt)
      atomicAdd(l_part + (size_t)(b * NH + h) * SEQ + q0 + qt * 16 + l16, lAcc[qt]);
  }

  // O^T -> transposed accumulator [b][h][d][q] (lane-coalesced atomics)
#pragma unroll
  for (int qt = 0; qt < 2; ++qt)
#pragma unroll
    for (int d16 = 0; d16 < 4; ++d16)
#pragma unroll
      for (int r = 0; r < 4; ++r) {
        int d = d16 * 16 + quad * 4 + r;
        atomicAdd(attn_pot + ((size_t)(b * NH + h) * DH + d) * SEQ + q0 + qt * 16 + l16,
                  O[qt][d16][r]);
      }
}

extern "C" void kernel_launch(void* const* d_in, const int* in_sizes, int n_in,
                              void* d_out, int out_size, void* d_ws, size_t ws_size,
                              hipStream_t stream) {
  const float* hs   = (const float*)d_in[0];
  const float* mask = (const float*)d_in[1];
  const float* Wq   = (const float*)d_in[2];
  const float* bq   = (const float*)d_in[3];
  const float* Wk   = (const float*)d_in[4];
  const float* bk   = (const float*)d_in[5];
  const float* Wv   = (const float*)d_in[6];
  const float* bv   = (const float*)d_in[7];
  const float* Wo   = (const float*)d_in[8];
  const float* bo   = (const float*)d_in[9];
  float* out = (float*)d_out;
  char* ws = (char*)d_ws;
  const size_t MiB = 1048576;

  unsigned short* hs_pk   = (unsigned short*)(ws);              // [0,8) dead after QKV gemm
  unsigned short* qkvproj = (unsigned short*)(ws + 8 * MiB);    // [8,20) dead after rope
  float*          attn_pot= (float*)(ws);                       // [0,16) after rope ([b][h][d][q])
  float*          l_part  = (float*)(ws + 16 * MiB);            // [16,16.25)
  unsigned short* Wqkv_hi = (unsigned short*)(ws + 20 * MiB);   // [20,23) dead after QKV gemm
  unsigned short* Wo_hi   = (unsigned short*)(ws + 20 * MiB);   // [20,22) after QKV gemm
  unsigned short* Wo_lo   = (unsigned short*)(ws + 22 * MiB);   // [22,24)
  unsigned short* Qpk_h   = (unsigned short*)(ws + 24 * MiB);   // [24,32) dead after attn
  unsigned short* Qpk_l   = (unsigned short*)(ws + 32 * MiB);   // [32,40) dead after attn
  unsigned short* ao_hi   = (unsigned short*)(ws + 24 * MiB);   // reuse
  unsigned short* ao_lo   = (unsigned short*)(ws + 32 * MiB);   // reuse
  unsigned short* Kpk     = (unsigned short*)(ws + 40 * MiB);   // [40,42)
  unsigned short* Vpk     = (unsigned short*)(ws + 42 * MiB);   // [42,44)
  float*          bias_c  = (float*)(ws + 44 * MiB);            // 6 KB

  // --- pack inputs ---
  pack_a_kernel<false><<<2048, 256, 0, stream>>>(hs, hs_pk, nullptr);
  pack_b_kernel<false><<<512, 256, 0, stream>>>(Wq, Wqkv_hi, nullptr, 1024);
  pack_b_kernel<false><<<128, 256, 0, stream>>>(Wk, Wqkv_hi + (size_t)64 * 2048 * 8, nullptr, 256);
  pack_b_kernel<false><<<128, 256, 0, stream>>>(Wv, Wqkv_hi + (size_t)80 * 2048 * 8, nullptr, 256);
  bias_cat_kernel<<<6, 256, 0, stream>>>(bq, bk, bv, bias_c);

  // --- fused QKV projection (bf16 MFMA, N=1536) ---
  gemm_pk_kernel<1, true><<<dim3(12, 64), 256, 0, stream>>>(
      hs_pk, nullptr, Wqkv_hi, nullptr, bias_c, qkvproj, 1536);

  pack_b_kernel<true><<<512, 256, 0, stream>>>(Wo, Wo_hi, Wo_lo, 1024);

  // --- rope + rmsnorm -> frag-major packed Q/K/V ---
  rope_norm_q_kernel<<<dim3(SEQ, BATCH), dim3(1024), 0, stream>>>(qkvproj, Qpk_h, Qpk_l);
  rope_norm_kv_kernel<<<dim3(SEQ, BATCH), dim3(256), 0, stream>>>(qkvproj, Kpk, Vpk);

  // --- zero partial accumulators, then LDS-free transposed attention ---
  hipMemsetAsync(ws, 0, 16 * MiB + 262144, stream);
  attn_mfma4_kernel<<<dim3(SEQ / 32, NKV * 2, BATCH), 256, 0, stream>>>(
      Qpk_h, Qpk_l, Kpk, Vpk, mask, attn_pot, l_part);

  // --- O projection: normalize+pack from transposed buffer, 3-chain GEMM ---
  pack_a_norm_kernel<<<2048, 256, 0, stream>>>(attn_pot, l_part, ao_hi, ao_lo);
  gemm_pk_kernel<3, false><<<dim3(8, 64), 256, 0, stream>>>(
      ao_hi, ao_lo, Wo_hi, Wo_lo, bo, out, 1024);
}

// Round 8
// 326.184 us; speedup vs baseline: 1.0827x; 1.0827x over previous
//
#include <hip/hip_runtime.h>
#include <cmath>

#define SEQ 2048
#define BATCH 2
#define HID 1024
#define NH 16
#define NKV 4
#define DH 64
#define KVDIM 256
#define K32C 32          // K=1024 -> 32 chunks of 32

typedef __attribute__((ext_vector_type(8))) short bf16x8;
typedef __attribute__((ext_vector_type(4))) float f32x4;
typedef __attribute__((ext_vector_type(4))) _Float16 f16x4;

static __device__ __forceinline__ unsigned short f2bf(float x) {
  union { float f; unsigned u; } v; v.f = x;
  unsigned r = v.u + 0x7fffu + ((v.u >> 16) & 1u);  // RNE
  return (unsigned short)(r >> 16);
}
static __device__ __forceinline__ float bf2f(unsigned short h) {
  union { unsigned u; float f; } v; v.u = ((unsigned)h) << 16;
  return v.f;
}
static __device__ __forceinline__ void gl_lds16(const unsigned short* g, unsigned short* l) {
  __builtin_amdgcn_global_load_lds(
      (const __attribute__((address_space(1))) unsigned int*)g,
      (__attribute__((address_space(3))) unsigned int*)l, 16, 0, 0);
}

// ---- pack A (fp32 [M][K=1024] row-major -> MFMA-A-frag-major bf16 hi[,lo]) ----
template<bool HILO>
__global__ __launch_bounds__(256) void pack_a_kernel(
    const float* __restrict__ A, unsigned short* __restrict__ hi,
    unsigned short* __restrict__ lo) {
  int gid = blockIdx.x * 256 + threadIdx.x;
  int lane = gid & 63;
  int k32 = (gid >> 6) & 31;
  int m16 = gid >> 11;
  int quad = lane >> 4, l16 = lane & 15;
  const float* src = A + (size_t)(m16 * 16 + l16) * 1024 + k32 * 32 + quad * 8;
  float4 a0 = *(const float4*)src;
  float4 a1 = *(const float4*)(src + 4);
  float v[8] = {a0.x, a0.y, a0.z, a0.w, a1.x, a1.y, a1.z, a1.w};
  unsigned short h[8], l[8];
#pragma unroll
  for (int j = 0; j < 8; ++j) {
    h[j] = f2bf(v[j]);
    if (HILO) l[j] = f2bf(v[j] - bf2f(h[j]));
  }
  *(bf16x8*)(hi + (size_t)gid * 8) = *(bf16x8*)h;
  if (HILO) *(bf16x8*)(lo + (size_t)gid * 8) = *(bf16x8*)l;
}

// ---- pack A from TRANSPOSED attention partials [b][h][d][q], normalize by l ----
__global__ __launch_bounds__(256) void pack_a_norm_kernel(
    const float* __restrict__ At, const float* __restrict__ lpart,
    unsigned short* __restrict__ hi, unsigned short* __restrict__ lo) {
  int gid = blockIdx.x * 256 + threadIdx.x;
  int lane = gid & 63;
  int k32 = (gid >> 6) & 31;
  int m16 = gid >> 11;
  int quad = lane >> 4, l16 = lane & 15;
  int m = m16 * 16 + l16;
  int b = m >> 11, s = m & 2047;
  int k0 = k32 * 32 + quad * 8;
  int h = k0 >> 6, d0 = k0 & 63;
  float inv = 1.0f / lpart[(size_t)(b * NH + h) * SEQ + s];
  const float* src = At + ((size_t)(b * NH + h) * DH + d0) * SEQ + s;
  unsigned short hh[8], ll[8];
#pragma unroll
  for (int j = 0; j < 8; ++j) {
    float x = src[(size_t)j * SEQ] * inv;
    hh[j] = f2bf(x);
    ll[j] = f2bf(x - bf2f(hh[j]));
  }
  *(bf16x8*)(hi + (size_t)gid * 8) = *(bf16x8*)hh;
  *(bf16x8*)(lo + (size_t)gid * 8) = *(bf16x8*)ll;
}

// ---- pack B (fp32 W [K=1024][Nsrc] -> MFMA-B-frag-major bf16 hi[,lo]) ----
template<bool HILO>
__global__ __launch_bounds__(256) void pack_b_kernel(
    const float* __restrict__ W, unsigned short* __restrict__ hi,
    unsigned short* __restrict__ lo, int Nsrc) {
  int gid = blockIdx.x * 256 + threadIdx.x;
  int lane = gid & 63;
  int k32 = (gid >> 6) & 31;
  int n16 = gid >> 11;
  int quad = lane >> 4, l16 = lane & 15;
  int n = n16 * 16 + l16, k = k32 * 32 + quad * 8;
  unsigned short h[8], l[8];
#pragma unroll
  for (int j = 0; j < 8; ++j) {
    float v = W[(size_t)(k + j) * Nsrc + n];
    h[j] = f2bf(v);
    if (HILO) l[j] = f2bf(v - bf2f(h[j]));
  }
  *(bf16x8*)(hi + (size_t)gid * 8) = *(bf16x8*)h;
  if (HILO) *(bf16x8*)(lo + (size_t)gid * 8) = *(bf16x8*)l;
}

__global__ __launch_bounds__(256) void bias_cat_kernel(
    const float* __restrict__ bq, const float* __restrict__ bk,
    const float* __restrict__ bv, float* __restrict__ dst) {
  int n = blockIdx.x * 256 + threadIdx.x;
  if (n < 1536)
    dst[n] = (n < 1024) ? bq[n] : (n < 1280 ? bk[n - 1024] : bv[n - 1280]);
}

// ---- packed-input MFMA GEMM (unchanged) ----
template<int CHAINS, bool OUTBF16>
__global__ __launch_bounds__(256) void gemm_pk_kernel(
    const unsigned short* __restrict__ Ah, const unsigned short* __restrict__ Al,
    const unsigned short* __restrict__ Bh, const unsigned short* __restrict__ Bl,
    const float* __restrict__ bias, void* __restrict__ Cout, int N) {
  constexpr int NCH = (CHAINS == 3) ? 2 : 1;
  __shared__ unsigned short Asm[NCH][4 * 512];
  __shared__ unsigned short Bsm[NCH][8 * 512];
  const int tid = threadIdx.x;
  const int wave = tid >> 6, lane = tid & 63;
  const int wr = wave >> 1, wc = wave & 1;
  const int quad = lane >> 4, l16 = lane & 15;
  const size_t abase = ((size_t)(blockIdx.y * 4 + wave) * K32C) * 64 + lane;
  const size_t bbase0 = ((size_t)(blockIdx.x * 8 + wave) * K32C) * 64 + lane;
  const size_t bbase1 = ((size_t)(blockIdx.x * 8 + wave + 4) * K32C) * 64 + lane;
  f32x4 acc[2][4] = {};
  for (int k32 = 0; k32 < K32C; ++k32) {
    __syncthreads();
    gl_lds16(Ah + (abase + (size_t)k32 * 64) * 8, &Asm[0][wave * 512]);
    gl_lds16(Bh + (bbase0 + (size_t)k32 * 64) * 8, &Bsm[0][wave * 512]);
    gl_lds16(Bh + (bbase1 + (size_t)k32 * 64) * 8, &Bsm[0][(wave + 4) * 512]);
    if (CHAINS == 3) {
      gl_lds16(Al + (abase + (size_t)k32 * 64) * 8, &Asm[1][wave * 512]);
      gl_lds16(Bl + (bbase0 + (size_t)k32 * 64) * 8, &Bsm[1][wave * 512]);
      gl_lds16(Bl + (bbase1 + (size_t)k32 * 64) * 8, &Bsm[1][(wave + 4) * 512]);
    }
    __syncthreads();
    bf16x8 af[2][NCH], bfr[4][NCH];
#pragma unroll
    for (int mt = 0; mt < 2; ++mt)
#pragma unroll
      for (int ch = 0; ch < NCH; ++ch)
        af[mt][ch] = *(const bf16x8*)&Asm[ch][((wr * 2 + mt) * 64 + lane) * 8];
#pragma unroll
    for (int nt = 0; nt < 4; ++nt)
#pragma unroll
      for (int ch = 0; ch < NCH; ++ch)
        bfr[nt][ch] = *(const bf16x8*)&Bsm[ch][((wc * 4 + nt) * 64 + lane) * 8];
#pragma unroll
    for (int mt = 0; mt < 2; ++mt)
#pragma unroll
      for (int nt = 0; nt < 4; ++nt) {
        acc[mt][nt] = __builtin_amdgcn_mfma_f32_16x16x32_bf16(af[mt][0], bfr[nt][0], acc[mt][nt], 0, 0, 0);
        if (CHAINS == 3) {
          acc[mt][nt] = __builtin_amdgcn_mfma_f32_16x16x32_bf16(af[mt][1], bfr[nt][0], acc[mt][nt], 0, 0, 0);
          acc[mt][nt] = __builtin_amdgcn_mfma_f32_16x16x32_bf16(af[mt][0], bfr[nt][1], acc[mt][nt], 0, 0, 0);
        }
      }
  }
  const int n0 = blockIdx.x * 128 + wc * 64;
  const int m0 = blockIdx.y * 64 + wr * 32;
#pragma unroll
  for (int mt = 0; mt < 2; ++mt)
#pragma unroll
    for (int nt = 0; nt < 4; ++nt)
#pragma unroll
      for (int r = 0; r < 4; ++r) {
        int gm = m0 + mt * 16 + quad * 4 + r;
        int n = n0 + nt * 16 + l16;
        float v = acc[mt][nt][r] + bias[n];
        if (OUTBF16)
          ((unsigned short*)Cout)[(size_t)gm * N + n] = f2bf(v);
        else
          ((float*)Cout)[(size_t)gm * N + n] = v;
      }
}

// ---- RoPE(half=512) + rmsnorm, Q -> A/B-frag-major packed bf16 hi/lo -------
__global__ __launch_bounds__(1024) void rope_norm_q_kernel(
    const unsigned short* __restrict__ qkv, unsigned short* __restrict__ Qh,
    unsigned short* __restrict__ Ql) {
  const int s = blockIdx.x, b = blockIdx.y;
  const int t = threadIdx.x;
  const unsigned short* row = qkv + ((size_t)b * SEQ + s) * 1536;
  const int j = t & 511;
  float invf = exp2f((float)j * (-13.287712379549449f / 512.0f));
  float ang = (float)s * invf;
  float c = cosf(ang), sn = sinf(ang);
  float x1 = bf2f(row[j]), x2 = bf2f(row[j + 512]);
  float val = (t < 512) ? (x1 * c - x2 * sn) : (x2 * c + x1 * sn);
  float ss = val * val;
#pragma unroll
  for (int off = 1; off < 64; off <<= 1) ss += __shfl_xor(ss, off);
  float rn = rsqrtf(ss * (1.0f / 64.0f) + 1.1920929e-07f);
  float v = val * rn;
  unsigned short hi = f2bf(v);
  unsigned short lo = f2bf(v - bf2f(hi));
  int h = t >> 6, d = t & 63;
  size_t o = (size_t)(b * NH + h) * 131072 +
             ((((size_t)(s >> 4) * 2 + (d >> 5)) * 64) + ((d >> 3) & 3) * 16 + (s & 15)) * 8 + (d & 7);
  Qh[o] = hi;
  Ql[o] = lo;
}

// ---- RoPE(half=128)+rmsnorm K -> frag-major bf16; V -> f16 16x16x16-A-frag --
// Vpk per (b,kvh): 4 d16 x 64 jc x 64 lanes x 8 f16 = 131072 halfs. Lane's 8
// halfs = [jt0: k-frag i0..3][jt1: i0..3] so one dwordx4 fetches both k-halves.
__global__ __launch_bounds__(256) void rope_norm_kv_kernel(
    const unsigned short* __restrict__ qkv, unsigned short* __restrict__ Kpk,
    unsigned short* __restrict__ Vpk) {
  const int s = blockIdx.x, b = blockIdx.y;
  const int t = threadIdx.x;
  const unsigned short* row = qkv + ((size_t)b * SEQ + s) * 1536;
  const int j = t & 127;
  float invf = exp2f((float)j * (-13.287712379549449f / 128.0f));
  float ang = (float)s * invf;
  float c = cosf(ang), sn = sinf(ang);
  float x1 = bf2f(row[1024 + j]), x2 = bf2f(row[1024 + 128 + j]);
  float val = (t < 128) ? (x1 * c - x2 * sn) : (x2 * c + x1 * sn);
  float ss = val * val;
#pragma unroll
  for (int off = 1; off < 64; off <<= 1) ss += __shfl_xor(ss, off);
  float rn = rsqrtf(ss * (1.0f / 64.0f) + 1.1920929e-07f);
  float kv = val * rn;
  int h = t >> 6, d = t & 63;
  size_t ko = (size_t)(b * NKV + h) * 131072 +
              ((((size_t)(s >> 4) * 2 + (d >> 5)) * 64) + ((d >> 3) & 3) * 16 + (s & 15)) * 8 + (d & 7);
  Kpk[ko] = f2bf(kv);
  // V f16 A-frag slot: d16=d>>4, l16=d&15, jc=s>>5, j'=s&31, jt=j'>>4,
  // quad=(j'>>2)&3, i=j'&3
  int d16 = d >> 4, l16v = d & 15, jc = s >> 5, jp = s & 31;
  int jt = jp >> 4, q4 = (jp >> 2) & 3, i = jp & 3;
  union { _Float16 f; unsigned short u; } vu;
  vu.f = (_Float16)bf2f(row[1280 + t]);
  size_t vo = (size_t)(b * NKV + h) * 131072 +
              (((size_t)(d16 * 64 + jc) * 64) + q4 * 16 + l16v) * 8 + jt * 4 + i;
  Vpk[vo] = vu.u;
}

// ------- MFMA attention v5: transposed scores, lane-local P, no LDS ---------
// C' = K·Q^T (16x16x32, A=K-frag, B=Q-frag, 2 chains). C'-layout: row=j_local
// =4*quad+r, col=q=l16 -> lane's 4 score regs per jt tile ARE the B-operand
// of v_mfma_f32_16x16x16_f16 (B[k=quad*4+i][n=l16]): P never leaves the lane.
// O^T = V^T·P^T via 16x16x16 f16 MFMA, V pre-packed f16 A-frag-major.
// Mask: coalesced float4 loads. No LDS, no barriers, no cross-lane in loop.
__global__ __launch_bounds__(256, 3) void attn_mfma5_kernel(
    const unsigned short* __restrict__ Qh, const unsigned short* __restrict__ Ql,
    const unsigned short* __restrict__ Kpk, const unsigned short* __restrict__ Vpk,
    const float* __restrict__ mask, float* __restrict__ attn_pot,
    float* __restrict__ l_part) {
  const int b = blockIdx.z;
  const int kvh = blockIdx.y >> 1, jh = blockIdx.y & 1;
  const int q0 = blockIdx.x * 32;
  const int tid = threadIdx.x, wave = tid >> 6, lane = tid & 63;
  const int quad = lane >> 4, l16 = lane & 15;
  const int h = kvh * 4 + wave;

  // Q B-frags (loop-invariant): [qt][kf][hi/lo]
  bf16x8 qbf[2][2][2];
  {
    const unsigned short* Qb_h = Qh + (size_t)(b * NH + h) * 131072;
    const unsigned short* Qb_l = Ql + (size_t)(b * NH + h) * 131072;
#pragma unroll
    for (int qt = 0; qt < 2; ++qt)
#pragma unroll
      for (int kf = 0; kf < 2; ++kf) {
        size_t o = ((((size_t)(q0 >> 4) + qt) * 2 + kf) * 64 + lane) * 8;
        qbf[qt][kf][0] = *(const bf16x8*)(Qb_h + o);
        qbf[qt][kf][1] = *(const bf16x8*)(Qb_l + o);
      }
  }

  const unsigned short* Kb = Kpk + (size_t)(b * NKV + kvh) * 131072;
  const unsigned short* Vb = Vpk + (size_t)(b * NKV + kvh) * 131072;
  const float* mrow0 = mask + ((size_t)b * SEQ + q0 + l16) * SEQ;
  const float* mrow1 = mrow0 + (size_t)16 * SEQ;

  f32x4 O[2][4] = {};            // [qt][d16], C-layout row=d_local, col=q_local
  float lAcc[2] = {0.0f, 0.0f};

  const int jbase = jh * (SEQ / 2);
  constexpr float SC = 0.18033688011112042f;   // 0.125 * log2(e)
  constexpr float L2E = 1.4426950408889634f;   // log2(e)
  constexpr float MOFF = -11.541560327111707f; // -8 * log2(e)

  for (int jc = 0; jc < 32; ++jc) {
    const int j0 = jbase + jc * 32;

    // K A-frags [jt][kf], V f16 A-frags [d16] (both jt halves in one b128)
    bf16x8 kfr[2][2];
    union { uint4 u; f16x4 h[2]; } vfr[4];
#pragma unroll
    for (int jt = 0; jt < 2; ++jt)
#pragma unroll
      for (int kf = 0; kf < 2; ++kf)
        kfr[jt][kf] = *(const bf16x8*)(Kb +
            ((((size_t)(j0 >> 4) + jt) * 2 + kf) * 64 + lane) * 8);
#pragma unroll
    for (int d16 = 0; d16 < 4; ++d16)
      vfr[d16].u = *(const uint4*)(Vb +
          (((size_t)d16 * 64 + (j0 >> 5)) * 64 + lane) * 8);
    float4 mk[2][2];
#pragma unroll
    for (int jt = 0; jt < 2; ++jt) {
      mk[jt][0] = *(const float4*)(mrow0 + j0 + jt * 16 + quad * 4);
      mk[jt][1] = *(const float4*)(mrow1 + j0 + jt * 16 + quad * 4);
    }

    // Transposed QK^T + softmax numerator -> lane-local f16 P^T B-frags
    f16x4 pf[2][2];  // [qt][jt]
#pragma unroll
    for (int jt = 0; jt < 2; ++jt)
#pragma unroll
      for (int qt = 0; qt < 2; ++qt) {
        f32x4 C = {};
        C = __builtin_amdgcn_mfma_f32_16x16x32_bf16(kfr[jt][0], qbf[qt][0][0], C, 0, 0, 0);
        C = __builtin_amdgcn_mfma_f32_16x16x32_bf16(kfr[jt][1], qbf[qt][1][0], C, 0, 0, 0);
        C = __builtin_amdgcn_mfma_f32_16x16x32_bf16(kfr[jt][0], qbf[qt][0][1], C, 0, 0, 0);
        C = __builtin_amdgcn_mfma_f32_16x16x32_bf16(kfr[jt][1], qbf[qt][1][1], C, 0, 0, 0);
        float4 m = mk[jt][qt];
        float ms[4] = {m.x, m.y, m.z, m.w};
#pragma unroll
        for (int r = 0; r < 4; ++r) {
          float p = exp2f(fmaf(C[r], SC, fmaf(ms[r], L2E, MOFF)));
          _Float16 ph = (_Float16)p;
          pf[qt][jt][r] = ph;
          lAcc[qt] += (float)ph;   // l consistent with rounded P
        }
      }

    // O^T += V^T · P^T  (16x16x16 f16, K=16 per jt half)
#pragma unroll
    for (int qt = 0; qt < 2; ++qt)
#pragma unroll
      for (int d16 = 0; d16 < 4; ++d16) {
        O[qt][d16] = __builtin_amdgcn_mfma_f32_16x16x16f16(vfr[d16].h[0], pf[qt][0], O[qt][d16], 0, 0, 0);
        O[qt][d16] = __builtin_amdgcn_mfma_f32_16x16x16f16(vfr[d16].h[1], pf[qt][1], O[qt][d16], 0, 0, 0);
      }
  }

  // l: reduce partial j-sums across quads (lanes differ in bits 4,5)
#pragma unroll
  for (int qt = 0; qt < 2; ++qt) {
    lAcc[qt] += __shfl_xor(lAcc[qt], 16);
    lAcc[qt] += __shfl_xor(lAcc[qt], 32);
  }
  if (quad == 0) {
#pragma unroll
    for (int qt = 0; qt < 2; ++qt)
      atomicAdd(l_part + (size_t)(b * NH + h) * SEQ + q0 + qt * 16 + l16, lAcc[qt]);
  }

  // O^T -> transposed accumulator [b][h][d][q] (lane-coalesced atomics)
#pragma unroll
  for (int qt = 0; qt < 2; ++qt)
#pragma unroll
    for (int d16 = 0; d16 < 4; ++d16)
#pragma unroll
      for (int r = 0; r < 4; ++r) {
        int d = d16 * 16 + quad * 4 + r;
        atomicAdd(attn_pot + ((size_t)(b * NH + h) * DH + d) * SEQ + q0 + qt * 16 + l16,
                  O[qt][d16][r]);
      }
}

extern "C" void kernel_launch(void* const* d_in, const int* in_sizes, int n_in,
                              void* d_out, int out_size, void* d_ws, size_t ws_size,
                              hipStream_t stream) {
  const float* hs   = (const float*)d_in[0];
  const float* mask = (const float*)d_in[1];
  const float* Wq   = (const float*)d_in[2];
  const float* bq   = (const float*)d_in[3];
  const float* Wk   = (const float*)d_in[4];
  const float* bk   = (const float*)d_in[5];
  const float* Wv   = (const float*)d_in[6];
  const float* bv   = (const float*)d_in[7];
  const float* Wo   = (const float*)d_in[8];
  const float* bo   = (const float*)d_in[9];
  float* out = (float*)d_out;
  char* ws = (char*)d_ws;
  const size_t MiB = 1048576;

  unsigned short* hs_pk   = (unsigned short*)(ws);              // [0,8) dead after QKV gemm
  unsigned short* qkvproj = (unsigned short*)(ws + 8 * MiB);    // [8,20) dead after rope
  float*          attn_pot= (float*)(ws);                       // [0,16) after rope ([b][h][d][q])
  float*          l_part  = (float*)(ws + 16 * MiB);            // [16,16.25)
  unsigned short* Wqkv_hi = (unsigned short*)(ws + 20 * MiB);   // [20,23) dead after QKV gemm
  unsigned short* Wo_hi   = (unsigned short*)(ws + 20 * MiB);   // [20,22) after QKV gemm
  unsigned short* Wo_lo   = (unsigned short*)(ws + 22 * MiB);   // [22,24)
  unsigned short* Qpk_h   = (unsigned short*)(ws + 24 * MiB);   // [24,32) dead after attn
  unsigned short* Qpk_l   = (unsigned short*)(ws + 32 * MiB);   // [32,40) dead after attn
  unsigned short* ao_hi   = (unsigned short*)(ws + 24 * MiB);   // reuse
  unsigned short* ao_lo   = (unsigned short*)(ws + 32 * MiB);   // reuse
  unsigned short* Kpk     = (unsigned short*)(ws + 40 * MiB);   // [40,42)
  unsigned short* Vpk     = (unsigned short*)(ws + 42 * MiB);   // [42,44)
  float*          bias_c  = (float*)(ws + 44 * MiB);            // 6 KB

  // --- pack inputs ---
  pack_a_kernel<false><<<2048, 256, 0, stream>>>(hs, hs_pk, nullptr);
  pack_b_kernel<false><<<512, 256, 0, stream>>>(Wq, Wqkv_hi, nullptr, 1024);
  pack_b_kernel<false><<<128, 256, 0, stream>>>(Wk, Wqkv_hi + (size_t)64 * 2048 * 8, nullptr, 256);
  pack_b_kernel<false><<<128, 256, 0, stream>>>(Wv, Wqkv_hi + (size_t)80 * 2048 * 8, nullptr, 256);
  bias_cat_kernel<<<6, 256, 0, stream>>>(bq, bk, bv, bias_c);

  // --- fused QKV projection (bf16 MFMA, N=1536) ---
  gemm_pk_kernel<1, true><<<dim3(12, 64), 256, 0, stream>>>(
      hs_pk, nullptr, Wqkv_hi, nullptr, bias_c, qkvproj, 1536);

  pack_b_kernel<true><<<512, 256, 0, stream>>>(Wo, Wo_hi, Wo_lo, 1024);

  // --- rope + rmsnorm -> frag-major packed Q/K/V ---
  rope_norm_q_kernel<<<dim3(SEQ, BATCH), dim3(1024), 0, stream>>>(qkvproj, Qpk_h, Qpk_l);
  rope_norm_kv_kernel<<<dim3(SEQ, BATCH), dim3(256), 0, stream>>>(qkvproj, Kpk, Vpk);

  // --- zero partial accumulators, then LDS-free transposed attention ---
  hipMemsetAsync(ws, 0, 16 * MiB + 262144, stream);
  attn_mfma5_kernel<<<dim3(SEQ / 32, NKV * 2, BATCH), 256, 0, stream>>>(
      Qpk_h, Qpk_l, Kpk, Vpk, mask, attn_pot, l_part);

  // --- O projection: normalize+pack from transposed buffer, 3-chain GEMM ---
  pack_a_norm_kernel<<<2048, 256, 0, stream>>>(attn_pot, l_part, ao_hi, ao_lo);
  gemm_pk_kernel<3, false><<<dim3(8, 64), 256, 0, stream>>>(
      ao_hi, ao_lo, Wo_hi, Wo_lo, bo, out, 1024);
}